// Round 1
// baseline (492.444 us; speedup 1.0000x reference)
//
#include <hip/hip_runtime.h>
#include <hip/hip_bf16.h>
#include <cstdint>

// MCRNNVAE eval forward, algebraically collapsed:
//   h_{t+1} = tanh(x_t@R_c + r0_c + h_t@Q_c)
//   mu_t    = x_t@N_c + h_t@M2_c + n0_c
// R,Q,N,M2,r0,n0 precomputed from the raw weights (exact linear algebra).
// Round 5: kernU2 fused into the recurrence (kernBU): x_t@R computed inline
// per step (4 extra hi-only MFMAs/wave), eliminating the U round-trip through
// HBM and one kernel launch. kernBU uses 16 waves/block (4/SIMD TLP),
// double-buffered LDS (ONE barrier/step), and 3 independent MFMA chains
// (x, h-hi, h-lo) to shorten dependency chains. kernC3 unchanged (proven).

typedef __attribute__((ext_vector_type(8))) short short8;
typedef __attribute__((ext_vector_type(4))) float float4v;

__device__ __forceinline__ float bf2f(unsigned short u){
  union { unsigned int i; float f; } v; v.i = ((unsigned int)u) << 16; return v.f;
}
__device__ __forceinline__ unsigned short f2bf(float f){
  union { float f; unsigned int i; } v; v.f = f;
  unsigned int r = v.i + 0x7fffu + ((v.i >> 16) & 1u);
  return (unsigned short)(r >> 16);
}
__device__ __forceinline__ void st_bf2(unsigned short* p, float a, float b){
  unsigned int pa = f2bf(a), pb = f2bf(b);
  *(unsigned int*)p = pa | (pb << 16);
}
__device__ __forceinline__ float ftanh(float x){
  x = fminf(15.f, fmaxf(-15.f, x));
  float e = __expf(2.f * x);
  return (e - 1.f) * __builtin_amdgcn_rcpf(e + 1.f);
}

__device__ __forceinline__ float dotSB(const float* __restrict__ a,
                                       const float* __restrict__ b, int K, int ldb){
  float s = 0.f;
  #pragma unroll 4
  for (int k = 0; k < K; ++k) s = fmaf(a[k], b[(size_t)k * ldb], s);
  return s;
}

// ---- precompute stage 1: T1 = We1@Wqm, T2 = We2@Wqm, c0a = be@Wqm + bqm
__global__ void pre1(const float* __restrict__ encW, const float* __restrict__ encb,
                     const float* __restrict__ Wqm, const float* __restrict__ bqm,
                     float* __restrict__ T1, float* __restrict__ T2, float* __restrict__ c0a){
  int i = blockIdx.x * 256 + threadIdx.x;
  if (i < 24576){
    int c = i >> 13, rr = (i >> 6) & 127, l = i & 63;
    T1[i] = dotSB(encW + ((size_t)c*384 + rr)*128, Wqm + (size_t)c*8192 + l, 128, 64);
  } else if (i < 73728){
    int j = i - 24576; int c = j >> 14, rr = (j >> 6) & 255, l = j & 63;
    T2[j] = dotSB(encW + ((size_t)c*384 + 128 + rr)*128, Wqm + (size_t)c*8192 + l, 128, 64);
  } else if (i < 73920){
    int j = i - 73728; int c = j >> 6, l = j & 63;
    c0a[j] = dotSB(encb + c*128, Wqm + (size_t)c*8192 + l, 128, 64) + bqm[j];
  }
}

// ---- stage 2: A = T1@Wz, Bm = T2@Wz, c0 = c0a@Wz + bz
__global__ void pre2(const float* __restrict__ T1, const float* __restrict__ T2,
                     const float* __restrict__ c0a, const float* __restrict__ Wz,
                     const float* __restrict__ bz,
                     float* __restrict__ A, float* __restrict__ Bm, float* __restrict__ c0){
  int i = blockIdx.x * 256 + threadIdx.x;
  if (i < 49152){
    int c = i >> 14, rr = (i >> 7) & 127, n = i & 127;
    A[i] = dotSB(T1 + ((size_t)c*128 + rr)*64, Wz + n, 64, 128);
  } else if (i < 147456){
    int j = i - 49152; int c = j >> 15, rr = (j >> 7) & 255, n = j & 127;
    Bm[j] = dotSB(T2 + ((size_t)c*256 + rr)*64, Wz + n, 64, 128);
  } else if (i < 147840){
    int j = i - 147456; int c = j >> 7, n = j & 127;
    c0[j] = dotSB(c0a + c*64, Wz + n, 64, 128) + bz[n];
  }
}

// ---- stage 3: P = Wi1 + A@Wi2; Q = Whh + Bm@Wi2; r = c0@Wi2 + bih + bhh;
//               D1 = A@Wd1; E1 = Wd2 + Bm@Wd1; m0a = c0@Wd1 + bd
__global__ void pre3(const float* __restrict__ A, const float* __restrict__ Bm,
                     const float* __restrict__ c0, const float* __restrict__ Wih,
                     const float* __restrict__ Whh, const float* __restrict__ bih,
                     const float* __restrict__ bhh, const float* __restrict__ decW,
                     const float* __restrict__ decb,
                     float* __restrict__ P, float* __restrict__ Q, float* __restrict__ r,
                     float* __restrict__ D1, float* __restrict__ E1, float* __restrict__ m0a){
  int i = blockIdx.x * 256 + threadIdx.x;
  const float* Wi2 = Wih + 128*256;
  if (i < 98304){
    int c = i >> 15, rr = (i >> 8) & 127, n = i & 255;
    P[i] = Wih[rr*256 + n] + dotSB(A + ((size_t)c*128 + rr)*128, Wi2 + n, 128, 256);
  } else if (i < 294912){
    int j = i - 98304; int c = j >> 16, rr = (j >> 8) & 255, n = j & 255;
    Q[j] = Whh[rr*256 + n] + dotSB(Bm + ((size_t)c*256 + rr)*128, Wi2 + n, 128, 256);
  } else if (i < 295680){
    int j = i - 294912; int c = j >> 8, n = j & 255;
    r[j] = dotSB(c0 + c*128, Wi2 + n, 128, 256) + bih[n] + bhh[n];
  } else if (i < 344832){
    int j = i - 295680; int c = j >> 14, rr = (j >> 7) & 127, n = j & 127;
    D1[j] = dotSB(A + ((size_t)c*128 + rr)*128, decW + (size_t)c*49152 + n, 128, 128);
  } else if (i < 443136){
    int j = i - 344832; int c = j >> 15, rr = (j >> 7) & 255, n = j & 127;
    E1[j] = decW[(size_t)c*49152 + (size_t)(128 + rr)*128 + n]
          + dotSB(Bm + ((size_t)c*256 + rr)*128, decW + (size_t)c*49152 + n, 128, 128);
  } else if (i < 443520){
    int j = i - 443136; int c = j >> 7, n = j & 127;
    m0a[j] = dotSB(c0 + c*128, decW + (size_t)c*49152 + n, 128, 128) + decb[j];
  }
}

// ---- stage 4: R = Wx@P; r0 = bx@P + r; M1 = D1@Wpm; M2 = E1@Wpm; m0 = m0a@Wpm + bpm
__global__ void pre4(const float* __restrict__ Wx, const float* __restrict__ bx,
                     const float* __restrict__ P, const float* __restrict__ r,
                     const float* __restrict__ D1, const float* __restrict__ E1,
                     const float* __restrict__ m0a, const float* __restrict__ Wpm,
                     const float* __restrict__ bpm,
                     float* __restrict__ R, float* __restrict__ r0,
                     float* __restrict__ M1, float* __restrict__ M2, float* __restrict__ m0){
  int i = blockIdx.x * 256 + threadIdx.x;
  if (i < 98304){
    int c = i >> 15, rr = (i >> 8) & 127, n = i & 255;
    R[i] = dotSB(Wx + ((size_t)c*128 + rr)*128, P + (size_t)c*32768 + n, 128, 256);
  } else if (i < 99072){
    int j = i - 98304; int c = j >> 8, n = j & 255;
    r0[j] = dotSB(bx + c*128, P + (size_t)c*32768 + n, 128, 256) + r[j];
  } else if (i < 148224){
    int j = i - 99072; int c = j >> 14, rr = (j >> 7) & 127, n = j & 127;
    M1[j] = dotSB(D1 + ((size_t)c*128 + rr)*128, Wpm + (size_t)c*16384 + n, 128, 128);
  } else if (i < 246528){
    int j = i - 148224; int c = j >> 15, rr = (j >> 7) & 255, n = j & 127;
    M2[j] = dotSB(E1 + ((size_t)c*256 + rr)*128, Wpm + (size_t)c*16384 + n, 128, 128);
  } else if (i < 246912){
    int j = i - 246528; int c = j >> 7, n = j & 127;
    m0[j] = dotSB(m0a + c*128, Wpm + (size_t)c*16384 + n, 128, 128) + bpm[j];
  }
}

// ---- stage 5: Nn = Wx@M1; n0 = bx@M1 + m0
__global__ void pre5(const float* __restrict__ Wx, const float* __restrict__ bx,
                     const float* __restrict__ M1, const float* __restrict__ m0,
                     float* __restrict__ Nn, float* __restrict__ n0){
  int i = blockIdx.x * 256 + threadIdx.x;
  if (i < 49152){
    int c = i >> 14, rr = (i >> 7) & 127, n = i & 127;
    Nn[i] = dotSB(Wx + ((size_t)c*128 + rr)*128, M1 + (size_t)c*16384 + n, 128, 128);
  } else if (i < 49536){
    int j = i - 49152; int c = j >> 7, n = j & 127;
    n0[j] = dotSB(bx + c*128, M1 + (size_t)c*16384 + n, 128, 128) + m0[j];
  }
}

#define MFMA_BF16 __builtin_amdgcn_mfma_f32_16x16x32_bf16

// ---- kernBU: fused recurrence h_{t+1} = tanh(x_t@R + r0 + h_t@Q), Hs[t] = h_t.
// 96 blocks = 3 channels x 32 (16 batch rows each), 1024 threads = 16 waves
// (4 waves/SIMD). Wave w owns 16 cols [16w,16w+16). Double-buffered LDS for
// h(hi/lo) and x(bf16): ONE barrier per step. Three independent MFMA chains
// per step (x-part len 4, h-hi len 8, h-lo len 8), summed before tanh.
// x_{t+1} prefetched to registers at iteration start (latency hidden under MFMAs).
__global__ __launch_bounds__(1024, 4)
void kernBU(const float* __restrict__ x, const float* __restrict__ Rg,
            const float* __restrict__ r0g, const float* __restrict__ Qg,
            const float* __restrict__ h0, unsigned short* __restrict__ Hs){
  __shared__ unsigned short hHi[2][16][264];   // +8 pad: row stride ≡ 4 dwords mod 32
  __shared__ unsigned short hLo[2][16][264];
  __shared__ unsigned short xsS[2][16][136];
  const int c  = blockIdx.x >> 5;
  const int b0 = (blockIdx.x & 31) << 4;
  const int w  = threadIdx.x >> 6;             // 0..15
  const int l  = threadIdx.x & 63;
  const int q  = l >> 4, m = l & 15;
  const int col = 16*w + m;                    // 16 waves cover cols 0..255
  const float* __restrict__ Qc = Qg + (size_t)c * 65536;   // [256][256]
  const float* __restrict__ Rc = Rg + (size_t)c * 32768;   // [128][256]

  // B-frags (bf16): B[k = 32kt+8q+j][n = col]  (layout proven in round-2/4 kernels)
  short8 qf[8];
  #pragma unroll
  for (int kt = 0; kt < 8; ++kt){
    union { short8 v; unsigned short u[8]; } tmp;
    #pragma unroll
    for (int j = 0; j < 8; ++j)
      tmp.u[j] = f2bf(Qc[(size_t)(32*kt + 8*q + j)*256 + col]);
    qf[kt] = tmp.v;
  }
  short8 rf[4];
  #pragma unroll
  for (int kt = 0; kt < 4; ++kt){
    union { short8 v; unsigned short u[8]; } tmp;
    #pragma unroll
    for (int j = 0; j < 8; ++j)
      tmp.u[j] = f2bf(Rc[(size_t)(32*kt + 8*q + j)*256 + col]);
    rf[kt] = tmp.v;
  }
  const float r0v = r0g[c*256 + col];

  // prologue: h0 -> LDS buf0 (hi/lo split) + hiR regs
  unsigned short hiR[4];
  #pragma unroll
  for (int r = 0; r < 4; ++r){
    const int row = 4*q + r;
    float v = h0[((size_t)c*512 + b0 + row)*256 + col];
    unsigned short hi = f2bf(v);
    hiR[r] = hi;
    hHi[0][row][col] = hi;
    hLo[0][row][col] = f2bf(v - bf2f(hi));
  }
  // prologue: x_0 -> LDS buf0 (each wave stages one row; lane l does cols 2l,2l+1)
  {
    const int c0 = l * 2;
    float2 v = *(const float2*)(x + ((size_t)(c*100 + 0)*512 + b0 + w)*128 + c0);
    st_bf2(&xsS[0][w][c0], v.x, v.y);
  }
  __syncthreads();

  #pragma unroll 1
  for (int t = 0; t < 100; ++t){
    const int cur = t & 1, nxt = cur ^ 1;

    // store h_t (bf16 hi) to Hs — fire-and-forget, overlaps with compute
    const size_t rowbase = (size_t)(c*100 + t)*512 + b0;
    #pragma unroll
    for (int r = 0; r < 4; ++r)
      Hs[(rowbase + 4*q + r)*256 + col] = hiR[r];

    // prefetch x_{t+1} to registers (consumed after the MFMAs)
    const int tn = (t < 99) ? t + 1 : 99;
    const int c0 = l * 2;
    float2 xv = *(const float2*)(x + ((size_t)(c*100 + tn)*512 + b0 + w)*128 + c0);

    // three independent accumulator chains: x-part (K=128), h-hi, h-lo (K=256)
    float4v accx = { r0v, r0v, r0v, r0v };
    float4v acch = { 0.f, 0.f, 0.f, 0.f };
    float4v accl = { 0.f, 0.f, 0.f, 0.f };
    #pragma unroll
    for (int kt = 0; kt < 4; ++kt){
      short8 ax  = *(const short8*)&xsS[cur][m][32*kt + 8*q];
      short8 ahi = *(const short8*)&hHi[cur][m][32*kt + 8*q];
      short8 alo = *(const short8*)&hLo[cur][m][32*kt + 8*q];
      accx = MFMA_BF16(ax,  rf[kt], accx, 0,0,0);
      acch = MFMA_BF16(ahi, qf[kt], acch, 0,0,0);
      accl = MFMA_BF16(alo, qf[kt], accl, 0,0,0);
    }
    #pragma unroll
    for (int kt = 4; kt < 8; ++kt){
      short8 ahi = *(const short8*)&hHi[cur][m][32*kt + 8*q];
      short8 alo = *(const short8*)&hLo[cur][m][32*kt + 8*q];
      acch = MFMA_BF16(ahi, qf[kt], acch, 0,0,0);
      accl = MFMA_BF16(alo, qf[kt], accl, 0,0,0);
    }

    float hn[4];
    hn[0] = ftanh(accx.x + acch.x + accl.x);
    hn[1] = ftanh(accx.y + acch.y + accl.y);
    hn[2] = ftanh(accx.z + acch.z + accl.z);
    hn[3] = ftanh(accx.w + acch.w + accl.w);

    // write h_{t+1} (hi/lo) and x_{t+1} into the NEXT buffers; prev-iter readers
    // of these buffers finished before the barrier that ended iteration t-1.
    #pragma unroll
    for (int r = 0; r < 4; ++r){
      const int row = 4*q + r;
      float v = hn[r];
      unsigned short hi = f2bf(v);
      hiR[r] = hi;
      hHi[nxt][row][col] = hi;
      hLo[nxt][row][col] = f2bf(v - bf2f(hi));
    }
    st_bf2(&xsS[nxt][w][c0], xv.x, xv.y);

    __syncthreads();   // single barrier per step (double-buffered LDS)
  }
}

// ---- kernC3: out = x@Nn + Hs@M2 + n0 via MFMA. 1200 blocks x 512 thr. (proven)
__global__ __launch_bounds__(512, 2)
void kernC3(const float* __restrict__ x, const unsigned short* __restrict__ Hs,
            const float* __restrict__ Nn, const float* __restrict__ M2,
            const float* __restrict__ n0, float* __restrict__ out){
  __shared__ unsigned short xs[128][136];
  const int m0 = blockIdx.x * 128;
  const int c  = m0 / 51200;
  const int w  = threadIdx.x >> 6;
  const int l  = threadIdx.x & 63;
  const int q  = l >> 4, m = l & 15;
  const int col = 16*w + m;
  const float* __restrict__ Nc  = Nn + (size_t)c * 16384;   // [128][128]
  const float* __restrict__ M2c = M2 + (size_t)c * 32768;   // [256][128]

  short8 bw[12];
  #pragma unroll
  for (int kt = 0; kt < 4; ++kt){
    union { short8 v; unsigned short u[8]; } tmp;
    #pragma unroll
    for (int j = 0; j < 8; ++j)
      tmp.u[j] = f2bf(Nc[(size_t)(32*kt + 8*q + j)*128 + col]);
    bw[kt] = tmp.v;
  }
  #pragma unroll
  for (int kt = 0; kt < 8; ++kt){
    union { short8 v; unsigned short u[8]; } tmp;
    #pragma unroll
    for (int j = 0; j < 8; ++j)
      tmp.u[j] = f2bf(M2c[(size_t)(32*kt + 8*q + j)*128 + col]);
    bw[4 + kt] = tmp.v;
  }
  const float nz = n0[c*128 + col];

  {
    const int r  = threadIdx.x >> 2;
    const int c0 = (threadIdx.x & 3) * 32;
    const float* xr = x + (size_t)(m0 + r)*128 + c0;
    #pragma unroll
    for (int i = 0; i < 8; ++i){
      float4 v = *(const float4*)(xr + 4*i);
      st_bf2(&xs[r][c0 + 4*i],     v.x, v.y);
      st_bf2(&xs[r][c0 + 4*i + 2], v.z, v.w);
    }
  }
  __syncthreads();

  #pragma unroll 1
  for (int mt = 0; mt < 8; ++mt){
    float4v aa = { nz, nz, nz, nz }, ab = { 0.f, 0.f, 0.f, 0.f };
    #pragma unroll
    for (int kt = 0; kt < 4; ++kt){
      short8 af = *(const short8*)&xs[16*mt + m][32*kt + 8*q];
      if (kt & 1) ab = MFMA_BF16(af, bw[kt], ab, 0,0,0);
      else        aa = MFMA_BF16(af, bw[kt], aa, 0,0,0);
    }
    const size_t mrow = (size_t)(m0 + 16*mt) + m;
    #pragma unroll
    for (int kt = 0; kt < 8; ++kt){
      short8 af = *(const short8*)&Hs[mrow*256 + 32*kt + 8*q];
      if (kt & 1) ab = MFMA_BF16(af, bw[4+kt], ab, 0,0,0);
      else        aa = MFMA_BF16(af, bw[4+kt], aa, 0,0,0);
    }
    float* ob = out + (size_t)(m0 + 16*mt + 4*q)*128 + col;
    ob[0]   = aa.x + ab.x;
    ob[128] = aa.y + ab.y;
    ob[256] = aa.z + ab.z;
    ob[384] = aa.w + ab.w;
  }
}

extern "C" void kernel_launch(void* const* d_in, const int* in_sizes, int n_in,
                              void* d_out, int out_size, void* d_ws, size_t ws_size,
                              hipStream_t stream){
  const float* x    = (const float*)d_in[0];
  const float* Wx   = (const float*)d_in[1];
  const float* bx   = (const float*)d_in[2];
  const float* encW = (const float*)d_in[3];
  const float* encb = (const float*)d_in[4];
  const float* Wqm  = (const float*)d_in[5];
  const float* bqm  = (const float*)d_in[6];
  const float* Wz   = (const float*)d_in[7];
  const float* bz   = (const float*)d_in[8];
  const float* decW = (const float*)d_in[9];
  const float* decb = (const float*)d_in[10];
  const float* Wpm  = (const float*)d_in[11];
  const float* bpm  = (const float*)d_in[12];
  const float* Wih  = (const float*)d_in[13];
  const float* Whh  = (const float*)d_in[14];
  const float* bih  = (const float*)d_in[15];
  const float* bhh  = (const float*)d_in[16];
  const float* h0   = (const float*)d_in[17];

  float* ws = (float*)d_ws;
  size_t off = 0;
  auto alloc = [&](size_t n){ float* p = ws + off; off += n; return p; };
  float* T1  = alloc(24576);  float* T2  = alloc(49152);  float* c0a = alloc(192);
  float* A   = alloc(49152);  float* Bm  = alloc(98304);  float* c0  = alloc(384);
  float* P   = alloc(98304);  float* Q   = alloc(196608); float* r   = alloc(768);
  float* D1  = alloc(49152);  float* E1  = alloc(98304);  float* m0a = alloc(384);
  float* R   = alloc(98304);  float* r0  = alloc(768);
  float* M1  = alloc(49152);  float* M2  = alloc(98304);  float* m0  = alloc(384);
  float* Nn  = alloc(49152);  float* n0  = alloc(384);
  // Hs: 39,321,600 bf16 elements = 19,660,800 float slots (full size).
  unsigned short* Hs = (unsigned short*)(ws + off); off += 19660800;

  hipLaunchKernelGGL(pre1, dim3(289),  dim3(256), 0, stream, encW, encb, Wqm, bqm, T1, T2, c0a);
  hipLaunchKernelGGL(pre2, dim3(578),  dim3(256), 0, stream, T1, T2, c0a, Wz, bz, A, Bm, c0);
  hipLaunchKernelGGL(pre3, dim3(1733), dim3(256), 0, stream, A, Bm, c0, Wih, Whh, bih, bhh,
                     decW, decb, P, Q, r, D1, E1, m0a);
  hipLaunchKernelGGL(pre4, dim3(965),  dim3(256), 0, stream, Wx, bx, P, r, D1, E1, m0a,
                     Wpm, bpm, R, r0, M1, M2, m0);
  hipLaunchKernelGGL(pre5, dim3(194),  dim3(256), 0, stream, Wx, bx, M1, m0, Nn, n0);
  hipLaunchKernelGGL(kernBU, dim3(96),   dim3(1024), 0, stream, x, R, r0, Q, h0, Hs);
  hipLaunchKernelGGL(kernC3, dim3(1200), dim3(512), 0, stream, x, Hs, Nn, M2, n0, (float*)d_out);
}